// Round 3
// baseline (234.934 us; speedup 1.0000x reference)
//
#include <hip/hip_runtime.h>

#define NN 4096
#define DIM 128
#define TN 16            // q-rows per block
#define TM 128           // m-tile size
#define MHALF (NN / 2)   // 2048 per m-half
#define NTILES (MHALF / TM)  // 16

typedef __attribute__((ext_vector_type(8))) short bf16x8;
typedef __attribute__((ext_vector_type(4))) float f32x4;

#define HR_STRIDE 136    // ushorts/row: 272B, 16B-aligned rows
#define HC_STRIDE 140    // ushorts/row: 280B, 8B-aligned rows
#define P_STRIDE  136

__device__ inline unsigned short f2bf(float x) {
    union { float f; unsigned u; } v; v.f = x;
    unsigned r = v.u + 0x7FFFu + ((v.u >> 16) & 1u);
    return (unsigned short)(r >> 16);
}

// ---------------- prep: hidden fp32 -> hb (bf16 row-major) + hbt (bf16 transposed) ----
__global__ __launch_bounds__(256) void prep_kernel(
    const float* __restrict__ hidden,
    unsigned short* __restrict__ hb,    // [NN][DIM]
    unsigned short* __restrict__ hbt)   // [DIM][NN]
{
    __shared__ unsigned short T[DIM][72];   // [d][m-in-block], padded
    const int tid = threadIdx.x;
    const int m0 = blockIdx.x * 64;
    #pragma unroll
    for (int it = 0; it < 8; ++it) {
        int idx = tid + 256 * it;          // 64 rows x 32 float4 chunks
        int row = idx >> 5;
        int c4  = (idx & 31) * 4;
        float4 v = *(const float4*)(hidden + (size_t)(m0 + row) * DIM + c4);
        ushort4 o;
        o.x = f2bf(v.x); o.y = f2bf(v.y); o.z = f2bf(v.z); o.w = f2bf(v.w);
        *(ushort4*)(hb + (size_t)(m0 + row) * DIM + c4) = o;
        T[c4 + 0][row] = o.x; T[c4 + 1][row] = o.y;
        T[c4 + 2][row] = o.z; T[c4 + 3][row] = o.w;
    }
    __syncthreads();
    #pragma unroll
    for (int it = 0; it < 8; ++it) {
        int idx = tid + 256 * it;          // 128 d-rows x 16 ushort4 chunks
        int d  = idx >> 4;
        int c4 = (idx & 15) * 4;
        ushort4 o;
        o.x = T[d][c4 + 0]; o.y = T[d][c4 + 1];
        o.z = T[d][c4 + 2]; o.w = T[d][c4 + 3];
        *(ushort4*)(hbt + (size_t)d * NN + m0 + c4) = o;
    }
}

// ---------------- main: flash-style, 512 thr (8 waves), split-m over 2 halves ----------
__global__ __launch_bounds__(512, 4) void gat_flash_kernel(
    const float* __restrict__ hidden,        // [NN][DIM] fp32 (for Q only)
    const unsigned short* __restrict__ hb,   // [NN][DIM] bf16
    const unsigned short* __restrict__ hbt,  // [DIM][NN] bf16
    const int*   __restrict__ adj,           // [NN][NN]
    const float* __restrict__ W,             // [4][DIM]
    const float* __restrict__ bvec,          // [4]
    float*       __restrict__ Opart,         // [512][TN][DIM]
    float*       __restrict__ ml)            // [512][TN][2]
{
    __shared__ __align__(16) unsigned short Hrow[TM * HR_STRIDE];   // 34816 B
    __shared__ __align__(16) unsigned short Hcol[DIM * HC_STRIDE];  // 35840 B
    __shared__ __align__(16) unsigned short Pl[TN * P_STRIDE];      // 4352 B
    __shared__ float redmax[8][16];
    __shared__ float redsum[8][16];

    const int tid  = threadIdx.x;
    const int w    = tid >> 6;        // wave 0..7
    const int lane = tid & 63;
    const int g    = lane >> 4;
    const int l15  = lane & 15;
    const int blk  = blockIdx.x;
    const int n0   = (blk >> 1) * TN;
    const int mbase = (blk & 1) * MHALF;
    const int msub = 16 * w;          // wave's m-slice (scores) / d-slice (PV)
    const float NEG = -9.0e15f;

    const float b0 = bvec[0], b1 = bvec[1], b2 = bvec[2], b3 = bvec[3];

    // ---- Q staging: q[k][r][d] = h[n0+r][d]*W[k][d] (fp32 source), bf16 into Hrow ----
    {
        int pair = tid >> 3;                 // 0..63 = k*16 + r
        int k = pair >> 4, r = pair & 15;
        int d0 = (tid & 7) * 16;
        const float* hrow = hidden + (size_t)(n0 + r) * DIM + d0;
        const float* wrow = W + k * DIM + d0;
        #pragma unroll
        for (int c = 0; c < 4; ++c) {
            float4 hv = *(const float4*)(hrow + 4 * c);
            float4 wv = *(const float4*)(wrow + 4 * c);
            ushort4 o;
            o.x = f2bf(hv.x * wv.x); o.y = f2bf(hv.y * wv.y);
            o.z = f2bf(hv.z * wv.z); o.w = f2bf(hv.w * wv.w);
            *(ushort4*)&Hrow[pair * HR_STRIDE + d0 + 4 * c] = o;
        }
    }
    __syncthreads();

    bf16x8 Af[4][4];
    #pragma unroll
    for (int k = 0; k < 4; ++k)
        #pragma unroll
        for (int ks = 0; ks < 4; ++ks)
            Af[k][ks] = *(const bf16x8*)&Hrow[(k * 16 + l15) * HR_STRIDE + ks * 32 + 8 * g];
    __syncthreads();

    float mrow[4], lrow[4];
    f32x4 Oacc;
    #pragma unroll
    for (int t = 0; t < 4; ++t) { mrow[t] = -INFINITY; lrow[t] = 0.f; }
    Oacc = (f32x4){0.f, 0.f, 0.f, 0.f};

    for (int tile = 0; tile < NTILES; ++tile) {
        const int mt0 = mbase + tile * TM;

        // adj prefetch for this wave's 16-col score slice
        int av[4];
        #pragma unroll
        for (int t = 0; t < 4; ++t)
            av[t] = adj[(size_t)(n0 + 4 * g + t) * NN + mt0 + msub + l15];

        __syncthreads();   // A: previous tile's PV reads done

        // ---- stage H tile (pure bf16 copies) ----
        #pragma unroll
        for (int it = 0; it < 4; ++it) {       // Hrow: 2048 x 16B chunks
            int id = tid + 512 * it;
            int m = id >> 4, c = id & 15;
            uint4 v = *(const uint4*)(hb + (size_t)(mt0 + m) * DIM + 8 * c);
            *(uint4*)&Hrow[m * HR_STRIDE + 8 * c] = v;
        }
        #pragma unroll
        for (int it = 0; it < 8; ++it) {       // Hcol: 4096 x 8B chunks
            int id = tid + 512 * it;
            int d = id >> 5, c = id & 31;
            uint2 v = *(const uint2*)(hbt + (size_t)d * NN + mt0 + 4 * c);
            *(uint2*)&Hcol[d * HC_STRIDE + 4 * c] = v;
        }
        __syncthreads();   // staged

        // ---- scores: S[k] = Q_k @ H^T for m-slice [mt0+msub, +16) ----
        f32x4 S[4];
        #pragma unroll
        for (int k = 0; k < 4; ++k) S[k] = (f32x4){0.f, 0.f, 0.f, 0.f};
        #pragma unroll
        for (int ks = 0; ks < 4; ++ks) {
            bf16x8 B = *(const bf16x8*)&Hrow[(msub + l15) * HR_STRIDE + ks * 32 + 8 * g];
            #pragma unroll
            for (int k = 0; k < 4; ++k)
                S[k] = __builtin_amdgcn_mfma_f32_16x16x32_bf16(Af[k][ks], B, S[k], 0, 0, 0);
        }

        // ---- selection + leaky relu; C layout row=4g+t, col=l15 ----
        float ev[4], rmax[4];
        #pragma unroll
        for (int t = 0; t < 4; ++t) {
            int a = av[t];
            float s = S[0][t] + b0;
            s = (a == 2) ? S[1][t] + b1 : s;
            s = (a == 3) ? S[2][t] + b2 : s;
            s = (a == 4) ? S[3][t] + b3 : s;
            float e = fmaxf(s, 0.2f * s);
            e = (a == 0) ? NEG : e;
            ev[t] = e;
            float v = e;
            v = fmaxf(v, __shfl_xor(v, 1));
            v = fmaxf(v, __shfl_xor(v, 2));
            v = fmaxf(v, __shfl_xor(v, 4));
            v = fmaxf(v, __shfl_xor(v, 8));
            rmax[t] = v;
        }
        if (l15 == 0) {
            #pragma unroll
            for (int t = 0; t < 4; ++t) redmax[w][4 * g + t] = rmax[t];
        }
        __syncthreads();   // B

        float alpha[4], mnew[4];
        #pragma unroll
        for (int t = 0; t < 4; ++t) {
            int r = 4 * g + t;
            float tm = redmax[0][r];
            #pragma unroll
            for (int ww = 1; ww < 8; ++ww) tm = fmaxf(tm, redmax[ww][r]);
            float mn = fmaxf(mrow[t], tm);
            alpha[t] = __expf(mrow[t] - mn);
            mnew[t] = mn; mrow[t] = mn;
            lrow[t] *= alpha[t];
        }
        float rs[4];
        #pragma unroll
        for (int t = 0; t < 4; ++t) {
            float p = __expf(ev[t] - mnew[t]);
            Pl[(4 * g + t) * P_STRIDE + msub + l15] = f2bf(p);
            float v = p;
            v += __shfl_xor(v, 1); v += __shfl_xor(v, 2);
            v += __shfl_xor(v, 4); v += __shfl_xor(v, 8);
            rs[t] = v;
        }
        if (l15 == 0) {
            #pragma unroll
            for (int t = 0; t < 4; ++t) redsum[w][4 * g + t] = rs[t];
        }
        #pragma unroll
        for (int t = 0; t < 4; ++t) Oacc[t] *= alpha[t];
        __syncthreads();   // C

        #pragma unroll
        for (int t = 0; t < 4; ++t) {
            int r = 4 * g + t;
            float s = redsum[0][r];
            #pragma unroll
            for (int ww = 1; ww < 8; ++ww) s += redsum[ww][r];
            lrow[t] += s;
        }

        // ---- PV: O[16r][d-slice msub..+16) += P[16][128] @ H[128][:] ----
        #pragma unroll
        for (int ks = 0; ks < 4; ++ks) {
            bf16x8 Pa = *(const bf16x8*)&Pl[l15 * P_STRIDE + ks * 32 + 8 * g];
            const unsigned short* hp = &Hcol[(msub + l15) * HC_STRIDE + ks * 32 + 8 * g];
            ushort4 u0 = *(const ushort4*)hp;
            ushort4 u1 = *(const ushort4*)(hp + 4);
            bf16x8 Bv;
            Bv[0] = (short)u0.x; Bv[1] = (short)u0.y; Bv[2] = (short)u0.z; Bv[3] = (short)u0.w;
            Bv[4] = (short)u1.x; Bv[5] = (short)u1.y; Bv[6] = (short)u1.z; Bv[7] = (short)u1.w;
            Oacc = __builtin_amdgcn_mfma_f32_16x16x32_bf16(Pa, Bv, Oacc, 0, 0, 0);
        }
    }

    // ---- epilogue: partial O (unnormalized) + (m,l) to workspace ----
    float* Ob = Opart + (size_t)blk * TN * DIM;
    #pragma unroll
    for (int t = 0; t < 4; ++t)
        Ob[(4 * g + t) * DIM + msub + l15] = Oacc[t];
    if (w == 0 && l15 == 0) {
        #pragma unroll
        for (int t = 0; t < 4; ++t) {
            ml[((size_t)blk * TN + 4 * g + t) * 2 + 0] = mrow[t];
            ml[((size_t)blk * TN + 4 * g + t) * 2 + 1] = lrow[t];
        }
    }
}

// ---------------- combine: merge the 2 m-halves, normalize --------------------------
__global__ __launch_bounds__(256) void combine_kernel(
    const float* __restrict__ Opart, const float* __restrict__ ml,
    float* __restrict__ out)
{
    int idx = blockIdx.x * 256 + threadIdx.x;   // over NN*DIM
    int r = idx >> 7, d = idx & (DIM - 1);
    int rb = r >> 4, rr = r & 15;
    int blk0 = rb * 2, blk1 = rb * 2 + 1;
    float m0 = ml[((size_t)blk0 * TN + rr) * 2 + 0];
    float l0 = ml[((size_t)blk0 * TN + rr) * 2 + 1];
    float m1 = ml[((size_t)blk1 * TN + rr) * 2 + 0];
    float l1 = ml[((size_t)blk1 * TN + rr) * 2 + 1];
    float M  = fmaxf(m0, m1);
    float a0 = __expf(m0 - M), a1 = __expf(m1 - M);
    float O0 = Opart[((size_t)blk0 * TN + rr) * DIM + d];
    float O1 = Opart[((size_t)blk1 * TN + rr) * DIM + d];
    out[idx] = (a0 * O0 + a1 * O1) / (a0 * l0 + a1 * l1);
}

extern "C" void kernel_launch(void* const* d_in, const int* in_sizes, int n_in,
                              void* d_out, int out_size, void* d_ws, size_t ws_size,
                              hipStream_t stream) {
    const float* hidden = (const float*)d_in[0];
    const int*   adj    = (const int*)d_in[1];
    const float* W      = (const float*)d_in[2];
    const float* b      = (const float*)d_in[3];
    float* out = (float*)d_out;

    char* ws = (char*)d_ws;
    unsigned short* hb  = (unsigned short*)ws;                       // 1 MB
    unsigned short* hbt = (unsigned short*)(ws + (size_t)NN * DIM * 2);  // 1 MB
    float* Opart = (float*)(ws + (size_t)2 * NN * DIM * 2);          // 512*16*128*4 = 4 MB
    float* ml    = (float*)(ws + (size_t)2 * NN * DIM * 2 + (size_t)512 * TN * DIM * 4);  // 64 KB

    prep_kernel<<<NN / 64, 256, 0, stream>>>(hidden, hb, hbt);
    gat_flash_kernel<<<512, 512, 0, stream>>>(hidden, hb, hbt, adj, W, b, Opart, ml);
    combine_kernel<<<NN * DIM / 256, 256, 0, stream>>>(Opart, ml, out);
}